// Round 1
// baseline (46443.509 us; speedup 1.0000x reference)
//
#include <hip/hip_runtime.h>
#include <stdint.h>

typedef unsigned int u32;
typedef unsigned long long u64;

#define AT_LD32(p)    __hip_atomic_load((u32*)(p), __ATOMIC_RELAXED, __HIP_MEMORY_SCOPE_AGENT)
#define AT_ST32(p,v)  __hip_atomic_store((u32*)(p), (v), __ATOMIC_RELAXED, __HIP_MEMORY_SCOPE_AGENT)
#define AT_LD64(p)    __hip_atomic_load((u64*)(p), __ATOMIC_RELAXED, __HIP_MEMORY_SCOPE_AGENT)
#define AT_ST64(p,v)  __hip_atomic_store((u64*)(p), (v), __ATOMIC_RELAXED, __HIP_MEMORY_SCOPE_AGENT)
#define AT_ADD32(p,v) __hip_atomic_fetch_add((u32*)(p), (v), __ATOMIC_RELAXED, __HIP_MEMORY_SCOPE_AGENT)

__device__ __forceinline__ float sigf(float x){ return 1.0f/(1.0f+__expf(-x)); }
__device__ __forceinline__ float tanhfast(float x){ float e=__expf(2.0f*x); return (e-1.0f)/(e+1.0f); }

// round-to-nearest-even f32->bf16 pair pack
__device__ __forceinline__ u32 pk2(float a, float b){
  u32 ua=__float_as_uint(a), ub=__float_as_uint(b);
  ua = (ua + 0x7fffu + ((ua>>16)&1u)) >> 16;
  ub = (ub + 0x7fffu + ((ub>>16)&1u)) >> 16;
  return ua | (ub<<16);
}
__device__ __forceinline__ float lo16(u32 u){ return __uint_as_float(u<<16); }
__device__ __forceinline__ float hi16(u32 u){ return __uint_as_float(u & 0xffff0000u); }

// ---- 2-level grid barrier: ctrl[l*32] leaf counters (l<8), ctrl[8*32] root, ctrl[9*32] gen
__device__ __forceinline__ void gbar(u32* ctrl, volatile int* bail){
  asm volatile("s_waitcnt vmcnt(0) lgkmcnt(0)" ::: "memory");
  __syncthreads();
  if (threadIdx.x == 0){
    u32* GEN = ctrl + 9*32;
    u32 g = AT_LD32(GEN);
    int leaf = blockIdx.x & 7;
    u32 n = AT_ADD32(ctrl + leaf*32, 1u);
    if (n == 31u){
      AT_ST32(ctrl + leaf*32, 0u);
      u32 r = AT_ADD32(ctrl + 8*32, 1u);
      if (r == 7u){ AT_ST32(ctrl + 8*32, 0u); AT_ADD32(GEN, 1u); }
    }
    long lim = (*bail) ? (1L<<8) : (1L<<22);
    long c = 0;
    while (AT_LD32(GEN) == g){
      __builtin_amdgcn_s_sleep(2);
      if (++c > lim){ *bail = 1; break; }
    }
  }
  __syncthreads();
}

__global__ void init_ctrl(u32* ctrl){
  if (threadIdx.x < 320) ctrl[threadIdx.x] = 0u;
}

__global__ void embed_k(const int* __restrict__ x, const float* __restrict__ emb,
                        float* __restrict__ emb_x){
  int gid = blockIdx.x*256 + threadIdx.x;   // 64*32*512 = 1048576
  int k  = gid & 511;
  int tb = gid >> 9;
  emb_x[gid] = emb[(size_t)x[tb]*512 + k];
}

// C[m][n] = bias[n] + sum_k A[m*lda+k] * B[n*ldb+boff+k]; grid=(N/256, M/8)
__global__ __launch_bounds__(256) void gemm_f32(
    const float* __restrict__ A, int lda,
    const float* __restrict__ Bm, int ldb, int boff,
    const float* __restrict__ bias,
    float* __restrict__ C, int ldc, int K)
{
  __shared__ float As[8][1028];
  int n  = blockIdx.x*256 + threadIdx.x;
  int m0 = blockIdx.y*8;
  for (int idx = threadIdx.x; idx < 8*K; idx += 256){
    int mm = idx / K, kk = idx - mm*K;
    As[mm][kk] = A[(size_t)(m0+mm)*lda + kk];
  }
  __syncthreads();
  float acc[8];
  float bs = bias[n];
  #pragma unroll
  for (int mm=0; mm<8; ++mm) acc[mm] = bs;
  const float* bp = Bm + (size_t)n*ldb + boff;
  for (int k = 0; k < K; k += 4){
    float4 w = *(const float4*)(bp + k);
    #pragma unroll
    for (int mm = 0; mm < 8; ++mm)
      acc[mm] += As[mm][k]*w.x + As[mm][k+1]*w.y + As[mm][k+2]*w.z + As[mm][k+3]*w.w;
  }
  #pragma unroll
  for (int mm = 0; mm < 8; ++mm)
    C[(size_t)(m0+mm)*ldc + n] = acc[mm];
}

// ---------------- persistent bidirectional encoder ----------------
// 256 blocks x 512 threads. dir = bid>>7, dblk = bid&127 owns 4 d-cols.
// thread: b = tid&31, dL = (tid>>5)&3, ks = tid>>7 (k-slice of 128).
__global__ __launch_bounds__(512) void enc_persist(
    const float* __restrict__ Whh_f, const float* __restrict__ Whh_b,
    const float* __restrict__ Gx_f,  const float* __restrict__ Gx_b,
    float* __restrict__ h_cat, u32* ctrl, u32* hbuf)
{
  __shared__ __align__(16) u32 uni[32*268];     // staged h (bf16 pairs), aliased as partials
  __shared__ __align__(16) u32 wldsb[16*256];   // 16 Whh rows, bf16-packed
  __shared__ float clds[128];
  __shared__ float exch[128];
  __shared__ int bail;

  const int tid = threadIdx.x, bid = blockIdx.x;
  const int dir = bid >> 7, dblk = bid & 127, d0 = dblk*4;
  const int b = tid & 31, grp = tid >> 5;
  const int dL = grp & 3, ks = grp >> 2;
  if (tid == 0) bail = 0;

  const float* Whh = dir ? Whh_b : Whh_f;
  const float* Gx  = dir ? Gx_b  : Gx_f;

  for (int idx = tid; idx < 16*256; idx += 512){
    int r = idx >> 8, p = idx & 255;
    int g = r >> 2, dl = r & 3;
    const float* wr = Whh + (size_t)(g*512 + d0 + dl)*512 + p*2;
    wldsb[idx] = pk2(wr[0], wr[1]);
  }

  u32* hb = hbuf + dir*2*8192;

  for (int t = 0; t < 64; ++t){
    int teff = dir ? (63 - t) : t;
    if (t > 0){
      const u32* src = hb + ((t&1)<<13);
      for (int idx = tid; idx < 8192; idx += 512)
        uni[(idx&31)*268 + (idx>>5)] = AT_LD32(src + idx);
    }
    __syncthreads();
    float a0=0.f,a1=0.f,a2=0.f,a3=0.f;
    if (t > 0){
      const u32* srow = uni + b*268 + ks*64;
      for (int c4 = 0; c4 < 16; ++c4){
        uint4 s4 = *(const uint4*)(srow + c4*4);
        float f0=lo16(s4.x),f1=hi16(s4.x),f2=lo16(s4.y),f3=hi16(s4.y);
        float f4=lo16(s4.z),f5=hi16(s4.z),f6=lo16(s4.w),f7=hi16(s4.w);
        int kp = ks*64 + c4*4;
        #pragma unroll
        for (int g = 0; g < 4; ++g){
          uint4 wq = *(const uint4*)(wldsb + (g*4+dL)*256 + kp);
          float s = f0*lo16(wq.x)+f1*hi16(wq.x)+f2*lo16(wq.y)+f3*hi16(wq.y)
                  + f4*lo16(wq.z)+f5*hi16(wq.z)+f6*lo16(wq.w)+f7*hi16(wq.w);
          if (g==0) a0+=s; else if (g==1) a1+=s; else if (g==2) a2+=s; else a3+=s;
        }
      }
    }
    __syncthreads();
    float* part = (float*)uni;
    { int base=(grp*32+b)*4; part[base]=a0; part[base+1]=a1; part[base+2]=a2; part[base+3]=a3; }
    __syncthreads();
    if (tid < 128){
      int bb = tid & 31, dl = tid >> 5;
      float r0=0.f,r1=0.f,r2=0.f,r3=0.f;
      #pragma unroll
      for (int kk = 0; kk < 4; ++kk){
        const float* p4 = part + (((kk<<2)|dl)*32 + bb)*4;
        r0+=p4[0]; r1+=p4[1]; r2+=p4[2]; r3+=p4[3];
      }
      const float* gx = Gx + ((size_t)teff*32 + bb)*2048;
      int d = d0 + dl;
      float gi=r0+gx[d], gf=r1+gx[512+d], gg=r2+gx[1024+d], go=r3+gx[1536+d];
      float c_ = (t==0) ? 0.f : clds[tid];
      float cn = sigf(gf)*c_ + sigf(gi)*tanhfast(gg);
      float hn = sigf(go)*tanhfast(cn);
      clds[tid] = cn;
      exch[tid] = hn;
      h_cat[((size_t)teff*32 + bb)*1024 + dir*512 + d] = hn;
    }
    __syncthreads();
    if (tid < 64){
      int bb = tid & 31, pp = tid >> 5;
      u32 u = pk2(exch[(pp*2)*32 + bb], exch[(pp*2+1)*32 + bb]);
      AT_ST32(hb + (((t+1)&1)<<13) + (dblk*2 + pp)*32 + bb, u);
    }
    gbar(ctrl, &bail);
  }
}

// ---------------- persistent decoder ----------------
// 256 blocks x 512 threads; block owns 2 d-cols (10 pre-cols incl. 5 gates).
// thread: b = tid&31, cp = (tid>>5)&1 (which d-col), ks = tid>>6 (k-slice of 64).
__global__ __launch_bounds__(512) void dec_persist(
    const float* __restrict__ Ws,    const float* __restrict__ Wx,
    const float* __restrict__ Wl,    const float* __restrict__ bl,
    const float* __restrict__ emb,   const float* __restrict__ hpart,
    u32* ctrl, u64* bests, u64* keys01, u32* sbuf, float* __restrict__ out)
{
  __shared__ __align__(16) u32 uni[32*268];   // staged s / y-emb (bf16 pairs); aliased partials/scratch
  __shared__ __align__(16) float wlds[10*512];
  __shared__ float prel[320];
  __shared__ float ypl[320];
  __shared__ float clds[64];
  __shared__ float exch[64];
  __shared__ int vst[32];
  __shared__ int bail;

  const int tid = threadIdx.x, bid = blockIdx.x;
  const int b = tid & 31, grp = tid >> 5;
  const int cp = grp & 1, ks = grp >> 1;
  const int d0 = bid*2;
  if (tid == 0) bail = 0;

  for (int idx = tid; idx < 10*512; idx += 512){
    int r = idx >> 9, k = idx & 511;
    int col = (r % 5)*512 + d0 + (r/5);
    wlds[idx] = Ws[(size_t)col*1024 + k];
  }

  for (int i = 0; i < 64; ++i){
    // ---- y-part (per-row constant contribution) ----
    if (i == 0){
      if (tid < 320) ypl[tid] = 0.f;
      __syncthreads();
    } else {
      for (int idx = tid; idx < 32*256; idx += 512){
        int bb = idx >> 8, p = idx & 255;
        int v = vst[bb]; v = v < 0 ? 0 : (v > 31999 ? 31999 : v);
        const float* er = emb + (size_t)v*512 + p*2;
        uni[bb*268 + p] = pk2(er[0], er[1]);
      }
      __syncthreads();
      if (tid < 320){
        int bb = tid & 31, c = tid >> 5;
        int col = (c % 5)*512 + d0 + (c/5);
        const float* wr = Wx + (size_t)col*1536;
        float a = 0.f;
        for (int it = 0; it < 128; ++it){
          float4 w4 = *(const float4*)(wr + it*4);
          u32 u0 = uni[bb*268 + it*2], u1 = uni[bb*268 + it*2 + 1];
          a += lo16(u0)*w4.x + hi16(u0)*w4.y + lo16(u1)*w4.z + hi16(u1)*w4.w;
        }
        ypl[c*32 + bb] = a;
      }
      __syncthreads();
    }
    if (tid < 64) clds[tid] = 0.f;
    __syncthreads();

    // ---- 64 horizontal steps ----
    for (int j = 0; j < 64; ++j){
      if (j > 0){
        const u32* sb = sbuf + ((j & 1) << 13);
        for (int idx = tid; idx < 8192; idx += 512)
          uni[(idx & 31)*268 + (idx >> 5)] = AT_LD32(sb + idx);
      }
      __syncthreads();
      float acc0=0.f,acc1=0.f,acc2=0.f,acc3=0.f,acc4=0.f;
      if (j > 0){
        const u32* srow = uni + b*268 + ks*32;
        const float* w0 = wlds + (cp*5+0)*512 + ks*64;
        const float* w1 = w0 + 512;
        const float* w2 = w0 + 1024;
        const float* w3 = w0 + 1536;
        const float* w4p= w0 + 2048;
        #pragma unroll
        for (int c4 = 0; c4 < 8; ++c4){
          uint4 s4 = *(const uint4*)(srow + c4*4);
          float f0=lo16(s4.x),f1=hi16(s4.x),f2=lo16(s4.y),f3=hi16(s4.y);
          float f4=lo16(s4.z),f5=hi16(s4.z),f6=lo16(s4.w),f7=hi16(s4.w);
          int ko = c4*8;
          float4 xa, xb;
          xa=*(const float4*)(w0+ko);  xb=*(const float4*)(w0+ko+4);
          acc0 += f0*xa.x+f1*xa.y+f2*xa.z+f3*xa.w + f4*xb.x+f5*xb.y+f6*xb.z+f7*xb.w;
          xa=*(const float4*)(w1+ko);  xb=*(const float4*)(w1+ko+4);
          acc1 += f0*xa.x+f1*xa.y+f2*xa.z+f3*xa.w + f4*xb.x+f5*xb.y+f6*xb.z+f7*xb.w;
          xa=*(const float4*)(w2+ko);  xb=*(const float4*)(w2+ko+4);
          acc2 += f0*xa.x+f1*xa.y+f2*xa.z+f3*xa.w + f4*xb.x+f5*xb.y+f6*xb.z+f7*xb.w;
          xa=*(const float4*)(w3+ko);  xb=*(const float4*)(w3+ko+4);
          acc3 += f0*xa.x+f1*xa.y+f2*xa.z+f3*xa.w + f4*xb.x+f5*xb.y+f6*xb.z+f7*xb.w;
          xa=*(const float4*)(w4p+ko); xb=*(const float4*)(w4p+ko+4);
          acc4 += f0*xa.x+f1*xa.y+f2*xa.z+f3*xa.w + f4*xb.x+f5*xb.y+f6*xb.z+f7*xb.w;
        }
      }
      __syncthreads();
      float* part = (float*)uni;
      { int base=(grp*32+b)*5;
        part[base]=acc0; part[base+1]=acc1; part[base+2]=acc2; part[base+3]=acc3; part[base+4]=acc4; }
      __syncthreads();
      if (tid < 320){
        int bb = tid & 31, c = tid >> 5;
        int cpx = c/5, q = c%5;
        float s = 0.f;
        #pragma unroll
        for (int kk = 0; kk < 8; ++kk) s += part[((cpx + 2*kk)*32 + bb)*5 + q];
        s += ypl[c*32+bb] + hpart[((size_t)j*32 + bb)*2560 + (q*512 + d0 + cpx)];
        prel[c*32 + bb] = s;
      }
      __syncthreads();
      if (tid < 64){
        int bb = tid & 31, cpx = tid >> 5;
        float gi = prel[(cpx*5+0)*32+bb];
        float gf = prel[(cpx*5+1)*32+bb];
        float go = prel[(cpx*5+2)*32+bb];
        float gl = prel[(cpx*5+3)*32+bb];
        float gg = prel[(cpx*5+4)*32+bb];
        float c_ = (j==0) ? 0.f : clds[tid];
        float cn = sigf(gf)*(sigf(gl)*c_) + sigf(gi)*tanhfast(gg);
        float sn = sigf(go)*tanhfast(cn);
        clds[tid] = cn;
        exch[tid] = sn;
      }
      __syncthreads();
      if (tid < 32){
        u32 u = pk2(exch[tid], exch[32+tid]);
        AT_ST32(sbuf + (((j+1)&1)<<13) + bid*32 + tid, u);
      }
      gbar(ctrl, &bail);
    }

    // ---- logits + argmax (s_J is in sbuf[0]) ----
    {
      for (int idx = tid; idx < 8192; idx += 512)
        uni[(idx & 31)*268 + (idx >> 5)] = AT_LD32(sbuf + idx);
      __syncthreads();
      const int vL = grp;
      const int vbase = bid*125;
      int nval = 125 - vL*8; nval = nval > 8 ? 8 : nval;
      float lac[8];
      int vv[8];
      #pragma unroll
      for (int n = 0; n < 8; ++n){
        int v = vbase + vL*8 + n;
        vv[n] = (n < nval) ? v : vbase;
        lac[n] = bl[vv[n]];
      }
      const u32* srow = uni + b*268;
      for (int pp = 0; pp < 128; ++pp){
        u32 u0 = srow[pp*2], u1 = srow[pp*2+1];
        float f0=lo16(u0), f1=hi16(u0), f2=lo16(u1), f3=hi16(u1);
        #pragma unroll
        for (int n = 0; n < 8; ++n){
          float4 w4 = *(const float4*)(Wl + (size_t)vv[n]*512 + pp*4);
          lac[n] += f0*w4.x + f1*w4.y + f2*w4.z + f3*w4.w;
        }
      }
      size_t obase = ((size_t)i*32 + b)*32000;
      u64 best = 0;
      for (int n = 0; n < nval; ++n){
        out[obase + vv[n]] = lac[n];
        u32 su = __float_as_uint(lac[n]);
        su = (su >> 31) ? ~su : (su | 0x80000000u);
        u64 key = ((u64)su << 32) | (u32)(~(u32)vv[n]);
        if (key > best) best = key;
      }
      __syncthreads();
      u64* scr = (u64*)uni;
      scr[grp*32 + b] = best;
      __syncthreads();
      if (tid < 32){
        u64 m = scr[tid];
        #pragma unroll
        for (int q2 = 1; q2 < 16; ++q2){ u64 x = scr[q2*32 + tid]; if (x > m) m = x; }
        AT_ST64(bests + bid*32 + tid, m);
      }
      gbar(ctrl, &bail);
      if (bid < 32){
        u64* scr2 = (u64*)uni;
        if (tid < 256) scr2[tid] = AT_LD64(bests + (size_t)tid*32 + bid);
        __syncthreads();
        for (int off = 128; off > 0; off >>= 1){
          if (tid < off){ u64 x = scr2[tid+off]; if (x > scr2[tid]) scr2[tid] = x; }
          __syncthreads();
        }
        if (tid == 0) AT_ST64(keys01 + (i&1)*32 + bid, scr2[0]);
      }
      gbar(ctrl, &bail);
      if (tid < 32){
        u64 kk = AT_LD64(keys01 + (i&1)*32 + tid);
        vst[tid] = (int)(~(u32)kk);
      }
      __syncthreads();
    }
  }
}

__global__ __launch_bounds__(256) void softmax_k(float* __restrict__ out){
  size_t row = blockIdx.x;
  float* p = out + row*32000;
  __shared__ float red[256];
  float s = 0.f;
  for (int v = threadIdx.x; v < 32000; v += 256) s += __expf(p[v]);
  red[threadIdx.x] = s;
  __syncthreads();
  for (int off = 128; off > 0; off >>= 1){
    if (threadIdx.x < off) red[threadIdx.x] += red[threadIdx.x+off];
    __syncthreads();
  }
  float Z = red[0];
  for (int v = threadIdx.x; v < 32000; v += 256) p[v] = __expf(p[v]) / Z;
}

extern "C" void kernel_launch(void* const* d_in, const int* in_sizes, int n_in,
                              void* d_out, int out_size, void* d_ws, size_t ws_size,
                              hipStream_t stream)
{
  const int*   x    = (const int*)d_in[0];
  const float* emb  = (const float*)d_in[2];
  const float* Wihf = (const float*)d_in[3];
  const float* Whhf = (const float*)d_in[4];
  const float* bf   = (const float*)d_in[5];
  const float* Wihb = (const float*)d_in[6];
  const float* Whhb = (const float*)d_in[7];
  const float* bb   = (const float*)d_in[8];
  const float* Wx   = (const float*)d_in[9];
  const float* Ws   = (const float*)d_in[10];
  const float* bc   = (const float*)d_in[11];
  const float* Wl   = (const float*)d_in[12];
  const float* bl   = (const float*)d_in[13];

  char* ws = (char*)d_ws;
  u32* ctrl   = (u32*)ws;                       // 1280 B counters (+ keys below)
  u64* keys   = (u64*)(ws + 2048);              // 2x32 u64
  u64* bests  = (u64*)(ws + 4096);              // 256x32 u64 = 64 KB
  u32* sbuf   = (u32*)(ws + 4096 + 65536);      // 2x8192 u32 = 64 KB
  u32* hbuf   = (u32*)(ws + 4096 + 2*65536);    // 2 dirs x 2 x 8192 u32 = 128 KB
  float* emb_x= (float*)(ws + 266240);          // 64*32*512 f32 = 4 MB
  float* h_cat= emb_x + (size_t)64*32*512;      // 8 MB
  float* Gxf  = h_cat + (size_t)64*32*1024;     // 16 MB
  float* Gxb  = Gxf   + (size_t)64*32*2048;     // 16 MB
  float* hpart= Gxf;                            // alias (Gx dead after encoder); 20 MB

  hipLaunchKernelGGL(init_ctrl, dim3(1), dim3(512), 0, stream, ctrl);
  hipLaunchKernelGGL(embed_k, dim3(4096), dim3(256), 0, stream, x, emb, emb_x);
  hipLaunchKernelGGL(gemm_f32, dim3(8,256), dim3(256), 0, stream,
                     emb_x, 512, Wihf, 512, 0, bf, Gxf, 2048, 512);
  hipLaunchKernelGGL(gemm_f32, dim3(8,256), dim3(256), 0, stream,
                     emb_x, 512, Wihb, 512, 0, bb, Gxb, 2048, 512);
  hipLaunchKernelGGL(enc_persist, dim3(256), dim3(512), 0, stream,
                     Whhf, Whhb, Gxf, Gxb, h_cat, ctrl, hbuf);
  hipLaunchKernelGGL(gemm_f32, dim3(10,256), dim3(256), 0, stream,
                     h_cat, 1024, Wx, 1536, 512, bc, hpart, 2560, 1024);
  hipLaunchKernelGGL(dec_persist, dim3(256), dim3(512), 0, stream,
                     Ws, Wx, Wl, bl, emb, hpart, ctrl, bests, keys, sbuf, (float*)d_out);
  hipLaunchKernelGGL(softmax_k, dim3(2048), dim3(256), 0, stream, (float*)d_out);
}